// Round 1
// baseline (899.784 us; speedup 1.0000x reference)
//
#include <hip/hip_runtime.h>
#include <cstdint>
#include <cstddef>

#define D_ 1024
#define H_ 4096
#define E_ 16
#define B_ 2048

constexpr int MROWS  = 64;            // rows per FFN block
constexpr int HCHUNK = 256;           // h-chunk per inner iteration
constexpr int HSPLIT = 4;             // H split across blocks
constexpr int HRANGE = H_ / HSPLIT;   // 1024
constexpr int KSTEP  = 32;
// padded LDS rows (ushorts): 32 data + 8 pad -> 80 B rows (stride 20 dwords, gcd(20,32)=4 -> <=2-way)
constexpr int LDW = 40;
constexpr int LDH = 264;              // hbuf: 256 data + 8 pad -> 528 B rows

typedef __attribute__((ext_vector_type(4))) float f32x4;
typedef __attribute__((ext_vector_type(8))) short bf16x8;

__device__ __forceinline__ unsigned short f2bf(float f) {
  unsigned u = __float_as_uint(f);
  u += 0x7fffu + ((u >> 16) & 1u);   // RNE
  return (unsigned short)(u >> 16);
}
__device__ __forceinline__ unsigned pack2(float a, float b) {
  return (unsigned)f2bf(a) | ((unsigned)f2bf(b) << 16);
}

// ---------------- gating: LayerNorm(x) @ normalize(keys) -> top2 -> routing lists ----------------
__global__ __launch_bounds__(256) void moe_gating(
    const float* __restrict__ x, const float* __restrict__ gamma,
    const float* __restrict__ beta, const float* __restrict__ keys,
    int* __restrict__ cnt, int* __restrict__ perm, float* __restrict__ pgate)
{
  const int b = blockIdx.x, t = threadIdx.x;
  const float4 xv = ((const float4*)(x + (size_t)b * D_))[t];  // d = 4t..4t+3
  float s  = xv.x + xv.y + xv.z + xv.w;
  float sq = xv.x*xv.x + xv.y*xv.y + xv.z*xv.z + xv.w*xv.w;
#pragma unroll
  for (int off = 32; off >= 1; off >>= 1) {
    s  += __shfl_down(s, off);
    sq += __shfl_down(sq, off);
  }
  __shared__ float ssum[4], ssq[4], sstat[2];
  if ((t & 63) == 0) { ssum[t >> 6] = s; ssq[t >> 6] = sq; }
  __syncthreads();
  if (t == 0) {
    float S = ssum[0] + ssum[1] + ssum[2] + ssum[3];
    float Q = ssq[0] + ssq[1] + ssq[2] + ssq[3];
    float mu  = S * (1.0f / D_);
    float var = Q * (1.0f / D_) - mu * mu;
    sstat[0] = mu; sstat[1] = rsqrtf(var + 1e-5f);
  }
  __syncthreads();
  const float mu = sstat[0], rstd = sstat[1];
  const float4 gv = ((const float4*)gamma)[t];
  const float4 bv = ((const float4*)beta)[t];
  float xn[4] = {(xv.x-mu)*rstd*gv.x+bv.x, (xv.y-mu)*rstd*gv.y+bv.y,
                 (xv.z-mu)*rstd*gv.z+bv.z, (xv.w-mu)*rstd*gv.w+bv.w};
  float acc[E_];
#pragma unroll
  for (int e2 = 0; e2 < E_; ++e2) acc[e2] = 0.f;
#pragma unroll
  for (int j = 0; j < 4; ++j) {
    const int d = 4*t + j;
    const float* kr = keys + (size_t)d * E_;
    float kv[E_];
#pragma unroll
    for (int e2 = 0; e2 < E_; ++e2) kv[e2] = kr[e2];
    float nq = 0.f;
#pragma unroll
    for (int e2 = 0; e2 < E_; ++e2) nq += kv[e2] * kv[e2];
    const float sc = xn[j] / fmaxf(sqrtf(nq), 1e-12f);
#pragma unroll
    for (int e2 = 0; e2 < E_; ++e2) acc[e2] += sc * kv[e2];
  }
  __shared__ float red[256][E_];
#pragma unroll
  for (int e2 = 0; e2 < E_; ++e2) red[t][e2] = acc[e2];
  __syncthreads();
  for (int s2 = 128; s2 >= 1; s2 >>= 1) {
    if (t < s2) {
#pragma unroll
      for (int e2 = 0; e2 < E_; ++e2) red[t][e2] += red[t + s2][e2];
    }
    __syncthreads();
  }
  if (t == 0) {
    float v0 = -1e30f; int e0 = 0;
    for (int e2 = 0; e2 < E_; ++e2) { float v = red[0][e2]; if (v > v0) { v0 = v; e0 = e2; } }
    float v1 = -1e30f; int e1 = 0;
    for (int e2 = 0; e2 < E_; ++e2) { if (e2 == e0) continue; float v = red[0][e2]; if (v > v1) { v1 = v; e1 = e2; } }
    const float g0 = 1.f / (1.f + __expf(v1 - v0));
    const float g1 = 1.f - g0;
    int p0 = atomicAdd(cnt + e0, 1);
    perm[e0 * B_ + p0] = b; pgate[e0 * B_ + p0] = g0;
    int p1 = atomicAdd(cnt + e1, 1);
    perm[e1 * B_ + p1] = b; pgate[e1 * B_ + p1] = g1;
  }
}

// ---------------- fused expert FFN: out += gate * (relu(X@W1+b1)@W2 + b2) ----------------
__global__ __launch_bounds__(512, 2) void moe_ffn(
    const float* __restrict__ X,  const float* __restrict__ W1,
    const float* __restrict__ b1, const float* __restrict__ W2,
    const float* __restrict__ b2, const int* __restrict__ cnt,
    const int* __restrict__ perm, const float* __restrict__ pgate,
    float* __restrict__ out)
{
  const int bx = blockIdx.x;
  const int e  = bx >> 7;          // 128 blocks per expert (32 mt x 4 hs)
  const int mt = (bx >> 2) & 31;
  const int hs = bx & 3;
  const int count = cnt[e];
  if (mt * MROWS >= count) return;

  const int t = threadIdx.x;
  const int w = t >> 6;
  const int lane = t & 63;
  const int l15 = lane & 15, l4 = lane >> 4;

  __shared__ __align__(16) unsigned short xs[MROWS * LDW];     //  5 KiB
  __shared__ __align__(16) unsigned short wt1[HCHUNK * LDW];   // 20 KiB
  __shared__ __align__(16) unsigned short wt2[D_ * LDW];       // 80 KiB
  __shared__ __align__(16) unsigned short hbuf[MROWS * LDH];   // 33 KiB
  __shared__ int   rows_s[MROWS];
  __shared__ float gate_s[MROWS];

  if (t < MROWS) {
    int slot = mt * MROWS + t;
    int idx  = slot < count ? slot : count - 1;
    rows_s[t] = perm[e * B_ + idx];
    gate_s[t] = (slot < count) ? pgate[e * B_ + idx] : 0.f;
  }
  __syncthreads();

  f32x4 oacc[4][8];
#pragma unroll
  for (int a = 0; a < 4; ++a)
#pragma unroll
    for (int c = 0; c < 8; ++c) oacc[a][c] = f32x4{0.f, 0.f, 0.f, 0.f};

  const float* W1e = W1 + (size_t)e * D_ * H_;
  const float* W2e = W2 + (size_t)e * H_ * D_;
  const int hbase0 = hs * HRANGE;

  const int xrow = t >> 3, xq = t & 7;
  const size_t xgbase = (size_t)rows_s[xrow] * D_ + xq * 4;

  for (int ch = 0; ch < HRANGE / HCHUNK; ++ch) {
    const int hb = hbase0 + ch * HCHUNK;

    // ---- GEMM1: h[64 x 256] = relu(X @ W1[:, hb:hb+256] + b1), K = 1024
    f32x4 hacc[4][2];
#pragma unroll
    for (int a = 0; a < 4; ++a)
#pragma unroll
      for (int c = 0; c < 2; ++c) hacc[a][c] = f32x4{0.f, 0.f, 0.f, 0.f};

    for (int kk = 0; kk < D_ / KSTEP; ++kk) {
      { // stage X slice [64][32] -> bf16
        const float4 v = *(const float4*)(X + xgbase + kk * KSTEP);
        *(uint2*)((char*)xs + xrow * 80 + xq * 8) =
            make_uint2(pack2(v.x, v.y), pack2(v.z, v.w));
      }
      // stage W1 panel transposed: wt1[n][k], n=h-col (256), k=d (32)
#pragma unroll
      for (int i = 0; i < 2; ++i) {
        const int p = t + i * 512;
        const int n = p & 255, koct = p >> 8;          // koct 0..3
        const float* src = W1e + (size_t)(kk * KSTEP + koct * 8) * H_ + (hb + n);
        float f0 = src[0],      f1 = src[H_],     f2 = src[2*H_],  f3 = src[3*H_];
        float f4 = src[4*H_],   f5 = src[5*H_],   f6 = src[6*H_],  f7 = src[7*H_];
        *(uint4*)((char*)wt1 + n * 80 + koct * 16) =
            make_uint4(pack2(f0,f1), pack2(f2,f3), pack2(f4,f5), pack2(f6,f7));
      }
      __syncthreads();
      bf16x8 af[4];
#pragma unroll
      for (int rf = 0; rf < 4; ++rf)
        af[rf] = *(const bf16x8*)((const char*)xs + (rf*16 + l15) * 80 + l4 * 16);
#pragma unroll
      for (int cf = 0; cf < 2; ++cf) {
        const bf16x8 bfr = *(const bf16x8*)((const char*)wt1 + (w*32 + cf*16 + l15) * 80 + l4 * 16);
#pragma unroll
        for (int rf = 0; rf < 4; ++rf)
          hacc[rf][cf] = __builtin_amdgcn_mfma_f32_16x16x32_bf16(af[rf], bfr, hacc[rf][cf], 0, 0, 0);
      }
      __syncthreads();
    }

    // h-store: relu(hacc + b1) -> hbuf bf16
#pragma unroll
    for (int cf = 0; cf < 2; ++cf) {
      const int col = w*32 + cf*16 + l15;
      const float bias = b1[e * H_ + hb + col];
#pragma unroll
      for (int rf = 0; rf < 4; ++rf)
#pragma unroll
        for (int r = 0; r < 4; ++r) {
          const int row = rf*16 + l4*4 + r;
          float v = hacc[rf][cf][r] + bias;
          v = fmaxf(v, 0.f);
          *((unsigned short*)((char*)hbuf + row * 528 + col * 2)) = f2bf(v);
        }
    }
    __syncthreads();

    // ---- GEMM2: out[64 x 1024] += h @ W2[hb:hb+256, :], K = 256
    for (int kk2 = 0; kk2 < HCHUNK / KSTEP; ++kk2) {
      const int habs = hb + kk2 * KSTEP;
#pragma unroll 4
      for (int i = 0; i < 8; ++i) {
        const int p = t + i * 512;
        const int n = p & 1023, koct = p >> 10;        // koct 0..3
        const float* src = W2e + (size_t)(habs + koct * 8) * D_ + n;
        float f0 = src[0],      f1 = src[D_],     f2 = src[2*D_],  f3 = src[3*D_];
        float f4 = src[4*D_],   f5 = src[5*D_],   f6 = src[6*D_],  f7 = src[7*D_];
        *(uint4*)((char*)wt2 + n * 80 + koct * 16) =
            make_uint4(pack2(f0,f1), pack2(f2,f3), pack2(f4,f5), pack2(f6,f7));
      }
      __syncthreads();
      bf16x8 af2[4];
#pragma unroll
      for (int rf = 0; rf < 4; ++rf)
        af2[rf] = *(const bf16x8*)((const char*)hbuf + (rf*16 + l15) * 528 + kk2 * 64 + l4 * 16);
#pragma unroll
      for (int cf = 0; cf < 8; ++cf) {
        const bf16x8 bfr = *(const bf16x8*)((const char*)wt2 + (w*128 + cf*16 + l15) * 80 + l4 * 16);
#pragma unroll
        for (int rf = 0; rf < 4; ++rf)
          oacc[rf][cf] = __builtin_amdgcn_mfma_f32_16x16x32_bf16(af2[rf], bfr, oacc[rf][cf], 0, 0, 0);
      }
      __syncthreads();
    }
  }

  // epilogue: out[row] += gate * (oacc + b2)   (b2 only once -> hs==0)
  int   rg[16];
  float gg[16];
#pragma unroll
  for (int rf = 0; rf < 4; ++rf)
#pragma unroll
    for (int r = 0; r < 4; ++r) {
      const int sl = rf*16 + l4*4 + r;
      rg[rf*4+r] = rows_s[sl];
      gg[rf*4+r] = gate_s[sl];
    }
#pragma unroll
  for (int cf = 0; cf < 8; ++cf) {
    const int col = w*128 + cf*16 + l15;
    const float b2v = (hs == 0) ? b2[e * D_ + col] : 0.f;
#pragma unroll
    for (int rf = 0; rf < 4; ++rf)
#pragma unroll
      for (int r = 0; r < 4; ++r) {
        const float v = (oacc[rf][cf][r] + b2v) * gg[rf*4+r];
        atomicAdd(out + (size_t)rg[rf*4+r] * D_ + col, v);
      }
  }
}

extern "C" void kernel_launch(void* const* d_in, const int* in_sizes, int n_in,
                              void* d_out, int out_size, void* d_ws, size_t ws_size,
                              hipStream_t stream) {
  const float* x     = (const float*)d_in[0];
  const float* gamma = (const float*)d_in[1];
  const float* beta  = (const float*)d_in[2];
  const float* keys  = (const float*)d_in[3];
  const float* W1    = (const float*)d_in[4];
  const float* b1    = (const float*)d_in[5];
  const float* W2    = (const float*)d_in[6];
  const float* b2    = (const float*)d_in[7];
  float* out = (float*)d_out;

  char* ws = (char*)d_ws;
  int*   cnt   = (int*)ws;                               // 16 ints
  int*   perm  = (int*)(ws + 256);                       // 16*2048 ints
  float* pgate = (float*)(ws + 256 + (size_t)E_*B_*4);   // 16*2048 floats

  (void)hipMemsetAsync(d_out, 0, (size_t)B_ * D_ * sizeof(float), stream);
  (void)hipMemsetAsync(cnt, 0, E_ * sizeof(int), stream);

  moe_gating<<<B_, 256, 0, stream>>>(x, gamma, beta, keys, cnt, perm, pgate);
  moe_ffn<<<E_ * 32 * HSPLIT, 512, 0, stream>>>(x, W1, b1, W2, b2, cnt, perm, pgate, out);
}

// Round 2
// 419.533 us; speedup vs baseline: 2.1447x; 2.1447x over previous
//
#include <hip/hip_runtime.h>
#include <cstdint>
#include <cstddef>

#define D_ 1024
#define H_ 4096
#define E_ 16
#define B_ 2048

constexpr int CAP = 384;     // per-expert row capacity in ws (mean 256, +8 sigma)
constexpr int MTT = 3;       // row tiles of 128 -> covers CAP

typedef __attribute__((ext_vector_type(4))) float f32x4;
typedef __attribute__((ext_vector_type(8))) short bf16x8;

__device__ __forceinline__ unsigned short f2bf(float f) {
  unsigned u = __float_as_uint(f);
  u += 0x7fffu + ((u >> 16) & 1u);   // RNE
  return (unsigned short)(u >> 16);
}
__device__ __forceinline__ unsigned pack2(float a, float b) {
  return (unsigned)f2bf(a) | ((unsigned)f2bf(b) << 16);
}

#define GLL16(g, l)                                                         \
  __builtin_amdgcn_global_load_lds(                                         \
      (const __attribute__((address_space(1))) void*)(g),                   \
      (__attribute__((address_space(3))) void*)(l), 16, 0, 0)

// ================= gating v2: LN(x)@norm(keys) -> top2 -> lists + bf16 X gather =================
__global__ __launch_bounds__(256) void moe_gating2(
    const float* __restrict__ x, const float* __restrict__ gamma,
    const float* __restrict__ beta, const float* __restrict__ keys,
    int* __restrict__ cnt, int* __restrict__ perm, float* __restrict__ pgate,
    unsigned short* __restrict__ xg)
{
  const int b = blockIdx.x, t = threadIdx.x;
  const float4 xv = ((const float4*)(x + (size_t)b * D_))[t];  // d = 4t..4t+3
  float s  = xv.x + xv.y + xv.z + xv.w;
  float sq = xv.x*xv.x + xv.y*xv.y + xv.z*xv.z + xv.w*xv.w;
#pragma unroll
  for (int off = 32; off >= 1; off >>= 1) {
    s  += __shfl_down(s, off);
    sq += __shfl_down(sq, off);
  }
  __shared__ float ssum[4], ssq[4], sstat[2];
  if ((t & 63) == 0) { ssum[t >> 6] = s; ssq[t >> 6] = sq; }
  __syncthreads();
  if (t == 0) {
    float S = ssum[0] + ssum[1] + ssum[2] + ssum[3];
    float Q = ssq[0] + ssq[1] + ssq[2] + ssq[3];
    float mu  = S * (1.0f / D_);
    float var = Q * (1.0f / D_) - mu * mu;
    sstat[0] = mu; sstat[1] = rsqrtf(var + 1e-5f);
  }
  __syncthreads();
  const float mu = sstat[0], rstd = sstat[1];
  const float4 gv = ((const float4*)gamma)[t];
  const float4 bv = ((const float4*)beta)[t];
  float xn[4] = {(xv.x-mu)*rstd*gv.x+bv.x, (xv.y-mu)*rstd*gv.y+bv.y,
                 (xv.z-mu)*rstd*gv.z+bv.z, (xv.w-mu)*rstd*gv.w+bv.w};
  float acc[E_];
#pragma unroll
  for (int e2 = 0; e2 < E_; ++e2) acc[e2] = 0.f;
#pragma unroll
  for (int j = 0; j < 4; ++j) {
    const int d = 4*t + j;
    const float* kr = keys + (size_t)d * E_;
    float kv[E_];
#pragma unroll
    for (int e2 = 0; e2 < E_; ++e2) kv[e2] = kr[e2];
    float nq = 0.f;
#pragma unroll
    for (int e2 = 0; e2 < E_; ++e2) nq += kv[e2] * kv[e2];
    const float sc = xn[j] / fmaxf(sqrtf(nq), 1e-12f);
#pragma unroll
    for (int e2 = 0; e2 < E_; ++e2) acc[e2] += sc * kv[e2];
  }
  __shared__ float red[256][E_];
#pragma unroll
  for (int e2 = 0; e2 < E_; ++e2) red[t][e2] = acc[e2];
  __syncthreads();
  for (int s2 = 128; s2 >= 1; s2 >>= 1) {
    if (t < s2) {
#pragma unroll
      for (int e2 = 0; e2 < E_; ++e2) red[t][e2] += red[t + s2][e2];
    }
    __syncthreads();
  }
  __shared__ int sE[2], sP[2];
  if (t == 0) {
    float v0 = -1e30f; int e0 = 0;
    for (int e2 = 0; e2 < E_; ++e2) { float v = red[0][e2]; if (v > v0) { v0 = v; e0 = e2; } }
    float v1 = -1e30f; int e1 = 0;
    for (int e2 = 0; e2 < E_; ++e2) { if (e2 == e0) continue; float v = red[0][e2]; if (v > v1) { v1 = v; e1 = e2; } }
    const float g0 = 1.f / (1.f + __expf(v1 - v0));
    const float g1 = 1.f - g0;
    int p0 = atomicAdd(cnt + e0, 1);
    perm[e0 * B_ + p0] = b; pgate[e0 * B_ + p0] = g0;
    int p1 = atomicAdd(cnt + e1, 1);
    perm[e1 * B_ + p1] = b; pgate[e1 * B_ + p1] = g1;
    sE[0] = e0; sP[0] = (p0 < CAP) ? p0 : -1;
    sE[1] = e1; sP[1] = (p1 < CAP) ? p1 : -1;
  }
  __syncthreads();
  const uint2 pk = make_uint2(pack2(xv.x, xv.y), pack2(xv.z, xv.w));
#pragma unroll
  for (int i = 0; i < 2; ++i) {
    if (sP[i] >= 0)
      ((uint2*)(xg + ((size_t)sE[i] * CAP + sP[i]) * D_))[t] = pk;
  }
}

// ================= grouped GEMM1: h = relu(Xg @ W1 + b1) -> hws (bf16) =================
// grid: E * MTT * 32 ; tile 128 rows x 128 cols, K=1024, Kstep=32
// A (bf16 X) via global_load_lds into swizzled LDS; B (fp32 W1) per-lane frag loads -> cvt
__global__ __launch_bounds__(512, 4) void moe_g1(
    const unsigned short* __restrict__ xg, const float* __restrict__ W1,
    const float* __restrict__ b1, const int* __restrict__ cnt,
    unsigned short* __restrict__ hws)
{
  const int bx = blockIdx.x;
  const int e   = bx / (MTT * 32);
  const int rem = bx - e * (MTT * 32);
  const int mt  = rem % MTT;                  // mt adjacent -> shared W1 panel locality
  const int nt  = rem / MTT;
  const int count = cnt[e];
  if (mt * 128 >= count) return;

  const int t = threadIdx.x, w = t >> 6, lane = t & 63;
  const int l15 = lane & 15, l4 = lane >> 4;
  const int wr = w >> 2, wc = w & 3;          // waves 2(rows) x 4(cols)
  const int nb = nt * 128 + wc * 32;

  __shared__ __align__(16) unsigned short xs[2][128 * 32];   // 8 KiB x2

  // staging source: chunk lin = t ; row = t>>2 ; swizzle c = (t&3) ^ ((row>>1)&3)
  const int srow = t >> 2;
  const int sc   = (t & 3) ^ ((srow >> 1) & 3);
  int gslot = mt * 128 + srow; if (gslot >= count) gslot = count - 1;
  const unsigned short* sbase = xg + ((size_t)e * CAP + gslot) * D_ + sc * 8;
  unsigned short* ldst0 = &xs[0][(size_t)w * 512];
  unsigned short* ldst1 = &xs[1][(size_t)w * 512];

  const float* W1e = W1 + (size_t)e * D_ * H_;
  const int col0 = nb + l15;
  const float* bbase = W1e + (size_t)(l4 * 8) * H_ + col0;

  const int cA = l4 ^ ((l15 >> 1) & 3);       // swizzled A-frag chunk

  f32x4 acc[4][2];
#pragma unroll
  for (int rf = 0; rf < 4; ++rf) { acc[rf][0] = f32x4{0,0,0,0}; acc[rf][1] = f32x4{0,0,0,0}; }

  float R0[16], R1[16];

#define STAGEA(kk, ld) GLL16(sbase + (kk) * 32, ld)
#define BLOADA(kk, R)                                                       \
  { const float* bp = bbase + (size_t)(kk) * 32 * H_;                       \
    _Pragma("unroll")                                                       \
    for (int j = 0; j < 8; ++j) {                                           \
      R[j]     = bp[(size_t)j * H_];                                        \
      R[8 + j] = bp[(size_t)j * H_ + 16];                                   \
    } }
#define COMPA(bufp, R)                                                      \
  { bf16x8 a[4];                                                            \
    _Pragma("unroll")                                                       \
    for (int rf = 0; rf < 4; ++rf) {                                        \
      const int row = wr * 64 + rf * 16 + l15;                              \
      a[rf] = *(const bf16x8*)&(bufp)[row * 32 + cA * 8];                   \
    }                                                                       \
    union { unsigned u[4]; bf16x8 v; } BB0, BB1;                            \
    _Pragma("unroll")                                                       \
    for (int i = 0; i < 4; ++i) {                                           \
      BB0.u[i] = pack2(R[2*i], R[2*i+1]);                                   \
      BB1.u[i] = pack2(R[8+2*i], R[8+2*i+1]);                               \
    }                                                                       \
    _Pragma("unroll")                                                       \
    for (int rf = 0; rf < 4; ++rf) {                                        \
      acc[rf][0] = __builtin_amdgcn_mfma_f32_16x16x32_bf16(a[rf], BB0.v, acc[rf][0], 0,0,0); \
      acc[rf][1] = __builtin_amdgcn_mfma_f32_16x16x32_bf16(a[rf], BB1.v, acc[rf][1], 0,0,0); \
    } }

  STAGEA(0, ldst0); BLOADA(0, R0);
  asm volatile("s_waitcnt vmcnt(0)" ::: "memory");   // drain group 0 + any hoisted loads
  for (int kk = 0; kk < 32; kk += 2) {
    if (kk + 1 < 32) {
      STAGEA(kk + 1, ldst1); BLOADA(kk + 1, R1);
      asm volatile("s_waitcnt vmcnt(17)" ::: "memory");
    } else {
      asm volatile("s_waitcnt vmcnt(0)" ::: "memory");
    }
    __builtin_amdgcn_s_barrier();
    COMPA(xs[0], R0);
    __builtin_amdgcn_s_barrier();
    if (kk + 2 < 32) {
      STAGEA(kk + 2, ldst0); BLOADA(kk + 2, R0);
      asm volatile("s_waitcnt vmcnt(17)" ::: "memory");
    } else {
      asm volatile("s_waitcnt vmcnt(0)" ::: "memory");
    }
    __builtin_amdgcn_s_barrier();
    COMPA(xs[1], R1);
    __builtin_amdgcn_s_barrier();
  }
#undef STAGEA
#undef BLOADA
#undef COMPA

  // epilogue: relu(acc + b1) -> hws bf16
  const float b1v0 = b1[e * H_ + nb + l15];
  const float b1v1 = b1[e * H_ + nb + 16 + l15];
  unsigned short* hrow = hws + (size_t)e * CAP * H_;
#pragma unroll
  for (int rf = 0; rf < 4; ++rf)
#pragma unroll
    for (int rr = 0; rr < 4; ++rr) {
      const int slot = mt * 128 + wr * 64 + rf * 16 + l4 * 4 + rr;
      unsigned short* hp = hrow + (size_t)slot * H_ + nb;
      hp[l15]      = f2bf(fmaxf(acc[rf][0][rr] + b1v0, 0.f));
      hp[16 + l15] = f2bf(fmaxf(acc[rf][1][rr] + b1v1, 0.f));
    }
}

// ================= grouped GEMM2: out += gate * (h @ W2 + b2) =================
// grid: E * MTT * 16 ; tile 128 rows x 64 cols, K=4096, Kstep=64
__global__ __launch_bounds__(512, 4) void moe_g2(
    const unsigned short* __restrict__ hws, const float* __restrict__ W2,
    const float* __restrict__ b2, const int* __restrict__ cnt,
    const int* __restrict__ perm, const float* __restrict__ pgate,
    float* __restrict__ out)
{
  const int bx = blockIdx.x;
  const int e   = bx / (MTT * 16);
  const int rem = bx - e * (MTT * 16);
  const int mt  = rem % MTT;
  const int nt  = rem / MTT;
  const int count = cnt[e];
  if (mt * 128 >= count) return;

  const int t = threadIdx.x, w = t >> 6, lane = t & 63;
  const int l15 = lane & 15, l4 = lane >> 4;
  const int wr = w >> 2, wc = w & 3;          // waves 2(rows) x 4(cols)
  const int nb = nt * 64 + wc * 16;

  __shared__ __align__(16) unsigned short hsb[2][128 * 64];  // 16 KiB x2

  // staging: 2 chunks/thread ; lin0 = w*128+lane, lin1 = +64 ; swizzle c = (lin&7)^(row&7)
  const int lin0 = w * 128 + lane, lin1 = lin0 + 64;
  const int r0c = lin0 >> 3, c0c = (lin0 & 7) ^ (r0c & 7);
  const int r1c = lin1 >> 3, c1c = (lin1 & 7) ^ (r1c & 7);
  const unsigned short* hbase = hws + ((size_t)e * CAP + mt * 128) * H_;
  const unsigned short* sb0 = hbase + (size_t)r0c * H_ + c0c * 8;
  const unsigned short* sb1 = hbase + (size_t)r1c * H_ + c1c * 8;
  unsigned short* ld0a = &hsb[0][(size_t)w * 1024];
  unsigned short* ld0b = &hsb[0][(size_t)w * 1024 + 512];
  unsigned short* ld1a = &hsb[1][(size_t)w * 1024];
  unsigned short* ld1b = &hsb[1][(size_t)w * 1024 + 512];

  const float* W2e = W2 + (size_t)e * H_ * D_;
  const int col = nb + l15;
  const float* bbase = W2e + (size_t)(l4 * 8) * D_ + col;

  const int cB0 = l4 ^ (l15 & 7);
  const int cB1 = (l4 + 4) ^ (l15 & 7);

  f32x4 acc[4];
#pragma unroll
  for (int rf = 0; rf < 4; ++rf) acc[rf] = f32x4{0,0,0,0};

  float R0[16], R1[16];

#define STAGEB(kk, la, lb) { GLL16(sb0 + (kk) * 64, la); GLL16(sb1 + (kk) * 64, lb); }
#define BLOADB(kk, R)                                                       \
  { const float* bp = bbase + (size_t)(kk) * 64 * D_;                       \
    _Pragma("unroll")                                                       \
    for (int j = 0; j < 8; ++j) {                                           \
      R[j]     = bp[(size_t)j * D_];                                        \
      R[8 + j] = bp[(size_t)(32 + j) * D_];                                 \
    } }
#define COMPB(bufp, R)                                                      \
  { bf16x8 a0[4], a1[4];                                                    \
    _Pragma("unroll")                                                       \
    for (int rf = 0; rf < 4; ++rf) {                                        \
      const int row = wr * 64 + rf * 16 + l15;                              \
      a0[rf] = *(const bf16x8*)&(bufp)[row * 64 + cB0 * 8];                 \
      a1[rf] = *(const bf16x8*)&(bufp)[row * 64 + cB1 * 8];                 \
    }                                                                       \
    union { unsigned u[4]; bf16x8 v; } BB0, BB1;                            \
    _Pragma("unroll")                                                       \
    for (int i = 0; i < 4; ++i) {                                           \
      BB0.u[i] = pack2(R[2*i], R[2*i+1]);                                   \
      BB1.u[i] = pack2(R[8+2*i], R[8+2*i+1]);                               \
    }                                                                       \
    _Pragma("unroll")                                                       \
    for (int rf = 0; rf < 4; ++rf)                                          \
      acc[rf] = __builtin_amdgcn_mfma_f32_16x16x32_bf16(a0[rf], BB0.v, acc[rf], 0,0,0); \
    _Pragma("unroll")                                                       \
    for (int rf = 0; rf < 4; ++rf)                                          \
      acc[rf] = __builtin_amdgcn_mfma_f32_16x16x32_bf16(a1[rf], BB1.v, acc[rf], 0,0,0); \
  }

  STAGEB(0, ld0a, ld0b); BLOADB(0, R0);
  asm volatile("s_waitcnt vmcnt(0)" ::: "memory");
  for (int kk = 0; kk < 64; kk += 2) {
    if (kk + 1 < 64) {
      STAGEB(kk + 1, ld1a, ld1b); BLOADB(kk + 1, R1);
      asm volatile("s_waitcnt vmcnt(18)" ::: "memory");
    } else {
      asm volatile("s_waitcnt vmcnt(0)" ::: "memory");
    }
    __builtin_amdgcn_s_barrier();
    COMPB(hsb[0], R0);
    __builtin_amdgcn_s_barrier();
    if (kk + 2 < 64) {
      STAGEB(kk + 2, ld0a, ld0b); BLOADB(kk + 2, R0);
      asm volatile("s_waitcnt vmcnt(18)" ::: "memory");
    } else {
      asm volatile("s_waitcnt vmcnt(0)" ::: "memory");
    }
    __builtin_amdgcn_s_barrier();
    COMPB(hsb[1], R1);
    __builtin_amdgcn_s_barrier();
  }
#undef STAGEB
#undef BLOADB
#undef COMPB

  const float b2v = b2[e * D_ + col];
  const int* pe = perm + e * B_;
  const float* ge = pgate + e * B_;
#pragma unroll
  for (int rf = 0; rf < 4; ++rf)
#pragma unroll
    for (int rr = 0; rr < 4; ++rr) {
      const int slot = mt * 128 + wr * 64 + rf * 16 + l4 * 4 + rr;
      const int sidx = slot < count ? slot : count - 1;
      const float g  = slot < count ? ge[slot] : 0.f;
      const int row  = pe[sidx];
      atomicAdd(out + (size_t)row * D_ + col, (acc[rf][rr] + b2v) * g);
    }
}

// ======================= fallback path (round-1 fused kernel) =======================
constexpr int MROWS  = 64;
constexpr int HCHUNK = 256;
constexpr int HSPLIT = 4;
constexpr int HRANGE = H_ / HSPLIT;
constexpr int KSTEP  = 32;
constexpr int LDW = 40;
constexpr int LDH = 264;

__global__ __launch_bounds__(256) void moe_gating(
    const float* __restrict__ x, const float* __restrict__ gamma,
    const float* __restrict__ beta, const float* __restrict__ keys,
    int* __restrict__ cnt, int* __restrict__ perm, float* __restrict__ pgate)
{
  const int b = blockIdx.x, t = threadIdx.x;
  const float4 xv = ((const float4*)(x + (size_t)b * D_))[t];
  float s  = xv.x + xv.y + xv.z + xv.w;
  float sq = xv.x*xv.x + xv.y*xv.y + xv.z*xv.z + xv.w*xv.w;
#pragma unroll
  for (int off = 32; off >= 1; off >>= 1) {
    s  += __shfl_down(s, off);
    sq += __shfl_down(sq, off);
  }
  __shared__ float ssum[4], ssq[4], sstat[2];
  if ((t & 63) == 0) { ssum[t >> 6] = s; ssq[t >> 6] = sq; }
  __syncthreads();
  if (t == 0) {
    float S = ssum[0] + ssum[1] + ssum[2] + ssum[3];
    float Q = ssq[0] + ssq[1] + ssq[2] + ssq[3];
    float mu  = S * (1.0f / D_);
    float var = Q * (1.0f / D_) - mu * mu;
    sstat[0] = mu; sstat[1] = rsqrtf(var + 1e-5f);
  }
  __syncthreads();
  const float mu = sstat[0], rstd = sstat[1];
  const float4 gv = ((const float4*)gamma)[t];
  const float4 bv = ((const float4*)beta)[t];
  float xn[4] = {(xv.x-mu)*rstd*gv.x+bv.x, (xv.y-mu)*rstd*gv.y+bv.y,
                 (xv.z-mu)*rstd*gv.z+bv.z, (xv.w-mu)*rstd*gv.w+bv.w};
  float acc[E_];
#pragma unroll
  for (int e2 = 0; e2 < E_; ++e2) acc[e2] = 0.f;
#pragma unroll
  for (int j = 0; j < 4; ++j) {
    const int d = 4*t + j;
    const float* kr = keys + (size_t)d * E_;
    float kv[E_];
#pragma unroll
    for (int e2 = 0; e2 < E_; ++e2) kv[e2] = kr[e2];
    float nq = 0.f;
#pragma unroll
    for (int e2 = 0; e2 < E_; ++e2) nq += kv[e2] * kv[e2];
    const float sc = xn[j] / fmaxf(sqrtf(nq), 1e-12f);
#pragma unroll
    for (int e2 = 0; e2 < E_; ++e2) acc[e2] += sc * kv[e2];
  }
  __shared__ float red[256][E_];
#pragma unroll
  for (int e2 = 0; e2 < E_; ++e2) red[t][e2] = acc[e2];
  __syncthreads();
  for (int s2 = 128; s2 >= 1; s2 >>= 1) {
    if (t < s2) {
#pragma unroll
      for (int e2 = 0; e2 < E_; ++e2) red[t][e2] += red[t + s2][e2];
    }
    __syncthreads();
  }
  if (t == 0) {
    float v0 = -1e30f; int e0 = 0;
    for (int e2 = 0; e2 < E_; ++e2) { float v = red[0][e2]; if (v > v0) { v0 = v; e0 = e2; } }
    float v1 = -1e30f; int e1 = 0;
    for (int e2 = 0; e2 < E_; ++e2) { if (e2 == e0) continue; float v = red[0][e2]; if (v > v1) { v1 = v; e1 = e2; } }
    const float g0 = 1.f / (1.f + __expf(v1 - v0));
    const float g1 = 1.f - g0;
    int p0 = atomicAdd(cnt + e0, 1);
    perm[e0 * B_ + p0] = b; pgate[e0 * B_ + p0] = g0;
    int p1 = atomicAdd(cnt + e1, 1);
    perm[e1 * B_ + p1] = b; pgate[e1 * B_ + p1] = g1;
  }
}

__global__ __launch_bounds__(512, 2) void moe_ffn(
    const float* __restrict__ X,  const float* __restrict__ W1,
    const float* __restrict__ b1, const float* __restrict__ W2,
    const float* __restrict__ b2, const int* __restrict__ cnt,
    const int* __restrict__ perm, const float* __restrict__ pgate,
    float* __restrict__ out)
{
  const int bx = blockIdx.x;
  const int e  = bx >> 7;
  const int mt = (bx >> 2) & 31;
  const int hs = bx & 3;
  const int count = cnt[e];
  if (mt * MROWS >= count) return;

  const int t = threadIdx.x;
  const int w = t >> 6;
  const int lane = t & 63;
  const int l15 = lane & 15, l4 = lane >> 4;

  __shared__ __align__(16) unsigned short xs[MROWS * LDW];
  __shared__ __align__(16) unsigned short wt1[HCHUNK * LDW];
  __shared__ __align__(16) unsigned short wt2[D_ * LDW];
  __shared__ __align__(16) unsigned short hbuf[MROWS * LDH];
  __shared__ int   rows_s[MROWS];
  __shared__ float gate_s[MROWS];

  if (t < MROWS) {
    int slot = mt * MROWS + t;
    int idx  = slot < count ? slot : count - 1;
    rows_s[t] = perm[e * B_ + idx];
    gate_s[t] = (slot < count) ? pgate[e * B_ + idx] : 0.f;
  }
  __syncthreads();

  f32x4 oacc[4][8];
#pragma unroll
  for (int a = 0; a < 4; ++a)
#pragma unroll
    for (int c = 0; c < 8; ++c) oacc[a][c] = f32x4{0.f, 0.f, 0.f, 0.f};

  const float* W1e = W1 + (size_t)e * D_ * H_;
  const float* W2e = W2 + (size_t)e * H_ * D_;
  const int hbase0 = hs * HRANGE;

  const int xrow = t >> 3, xq = t & 7;
  const size_t xgbase = (size_t)rows_s[xrow] * D_ + xq * 4;

  for (int ch = 0; ch < HRANGE / HCHUNK; ++ch) {
    const int hb = hbase0 + ch * HCHUNK;
    f32x4 hacc[4][2];
#pragma unroll
    for (int a = 0; a < 4; ++a)
#pragma unroll
      for (int c = 0; c < 2; ++c) hacc[a][c] = f32x4{0.f, 0.f, 0.f, 0.f};

    for (int kk = 0; kk < D_ / KSTEP; ++kk) {
      {
        const float4 v = *(const float4*)(X + xgbase + kk * KSTEP);
        *(uint2*)((char*)xs + xrow * 80 + xq * 8) =
            make_uint2(pack2(v.x, v.y), pack2(v.z, v.w));
      }
#pragma unroll
      for (int i = 0; i < 2; ++i) {
        const int p = t + i * 512;
        const int n = p & 255, koct = p >> 8;
        const float* src = W1e + (size_t)(kk * KSTEP + koct * 8) * H_ + (hb + n);
        float f0 = src[0],      f1 = src[H_],     f2 = src[2*H_],  f3 = src[3*H_];
        float f4 = src[4*H_],   f5 = src[5*H_],   f6 = src[6*H_],  f7 = src[7*H_];
        *(uint4*)((char*)wt1 + n * 80 + koct * 16) =
            make_uint4(pack2(f0,f1), pack2(f2,f3), pack2(f4,f5), pack2(f6,f7));
      }
      __syncthreads();
      bf16x8 af[4];
#pragma unroll
      for (int rf = 0; rf < 4; ++rf)
        af[rf] = *(const bf16x8*)((const char*)xs + (rf*16 + l15) * 80 + l4 * 16);
#pragma unroll
      for (int cf = 0; cf < 2; ++cf) {
        const bf16x8 bfr = *(const bf16x8*)((const char*)wt1 + (w*32 + cf*16 + l15) * 80 + l4 * 16);
#pragma unroll
        for (int rf = 0; rf < 4; ++rf)
          hacc[rf][cf] = __builtin_amdgcn_mfma_f32_16x16x32_bf16(af[rf], bfr, hacc[rf][cf], 0, 0, 0);
      }
      __syncthreads();
    }

#pragma unroll
    for (int cf = 0; cf < 2; ++cf) {
      const int col = w*32 + cf*16 + l15;
      const float bias = b1[e * H_ + hb + col];
#pragma unroll
      for (int rf = 0; rf < 4; ++rf)
#pragma unroll
        for (int r = 0; r < 4; ++r) {
          const int row = rf*16 + l4*4 + r;
          float v = hacc[rf][cf][r] + bias;
          v = fmaxf(v, 0.f);
          *((unsigned short*)((char*)hbuf + row * 528 + col * 2)) = f2bf(v);
        }
    }
    __syncthreads();

    for (int kk2 = 0; kk2 < HCHUNK / KSTEP; ++kk2) {
      const int habs = hb + kk2 * KSTEP;
#pragma unroll 4
      for (int i = 0; i < 8; ++i) {
        const int p = t + i * 512;
        const int n = p & 1023, koct = p >> 10;
        const float* src = W2e + (size_t)(habs + koct * 8) * D_ + n;
        float f0 = src[0],      f1 = src[D_],     f2 = src[2*D_],  f3 = src[3*D_];
        float f4 = src[4*D_],   f5 = src[5*D_],   f6 = src[6*D_],  f7 = src[7*D_];
        *(uint4*)((char*)wt2 + n * 80 + koct * 16) =
            make_uint4(pack2(f0,f1), pack2(f2,f3), pack2(f4,f5), pack2(f6,f7));
      }
      __syncthreads();
      bf16x8 af2[4];
#pragma unroll
      for (int rf = 0; rf < 4; ++rf)
        af2[rf] = *(const bf16x8*)((const char*)hbuf + (rf*16 + l15) * 528 + kk2 * 64 + l4 * 16);
#pragma unroll
      for (int cf = 0; cf < 8; ++cf) {
        const bf16x8 bfr = *(const bf16x8*)((const char*)wt2 + (w*128 + cf*16 + l15) * 80 + l4 * 16);
#pragma unroll
        for (int rf = 0; rf < 4; ++rf)
          oacc[rf][cf] = __builtin_amdgcn_mfma_f32_16x16x32_bf16(af2[rf], bfr, oacc[rf][cf], 0, 0, 0);
      }
      __syncthreads();
    }
  }

  int   rg[16];
  float gg[16];
#pragma unroll
  for (int rf = 0; rf < 4; ++rf)
#pragma unroll
    for (int r = 0; r < 4; ++r) {
      const int sl = rf*16 + l4*4 + r;
      rg[rf*4+r] = rows_s[sl];
      gg[rf*4+r] = gate_s[sl];
    }
#pragma unroll
  for (int cf = 0; cf < 8; ++cf) {
    const int col = w*128 + cf*16 + l15;
    const float b2v = (hs == 0) ? b2[e * D_ + col] : 0.f;
#pragma unroll
    for (int rf = 0; rf < 4; ++rf)
#pragma unroll
      for (int r = 0; r < 4; ++r) {
        const float v = (oacc[rf][cf][r] + b2v) * gg[rf*4+r];
        atomicAdd(out + (size_t)rg[rf*4+r] * D_ + col, v);
      }
  }
}

// ======================= launch =======================
extern "C" void kernel_launch(void* const* d_in, const int* in_sizes, int n_in,
                              void* d_out, int out_size, void* d_ws, size_t ws_size,
                              hipStream_t stream) {
  const float* x     = (const float*)d_in[0];
  const float* gamma = (const float*)d_in[1];
  const float* beta  = (const float*)d_in[2];
  const float* keys  = (const float*)d_in[3];
  const float* W1    = (const float*)d_in[4];
  const float* b1    = (const float*)d_in[5];
  const float* W2    = (const float*)d_in[6];
  const float* b2    = (const float*)d_in[7];
  float* out = (float*)d_out;

  char* ws = (char*)d_ws;
  int*   cnt   = (int*)ws;                         // 256 B
  int*   perm  = (int*)(ws + 256);                 // 128 KiB
  float* pgate = (float*)(ws + 256 + 131072);      // 128 KiB

  const size_t OFF_XG = 262400;                                    // aligned
  const size_t OFF_H  = OFF_XG + (size_t)E_ * CAP * D_ * 2;        // +12 MiB
  const size_t NEED   = OFF_H + (size_t)E_ * CAP * H_ * 2;         // +48 MiB

  (void)hipMemsetAsync(d_out, 0, (size_t)B_ * D_ * sizeof(float), stream);
  (void)hipMemsetAsync(cnt, 0, E_ * sizeof(int), stream);

  if (ws_size >= NEED) {
    unsigned short* xg  = (unsigned short*)(ws + OFF_XG);
    unsigned short* hws = (unsigned short*)(ws + OFF_H);
    moe_gating2<<<B_, 256, 0, stream>>>(x, gamma, beta, keys, cnt, perm, pgate, xg);
    moe_g1<<<E_ * MTT * 32, 512, 0, stream>>>(xg, W1, b1, cnt, hws);
    moe_g2<<<E_ * MTT * 16, 512, 0, stream>>>(hws, W2, b2, cnt, perm, pgate, out);
  } else {
    moe_gating<<<B_, 256, 0, stream>>>(x, gamma, beta, keys, cnt, perm, pgate);
    moe_ffn<<<E_ * 32 * HSPLIT, 512, 0, stream>>>(x, W1, b1, W2, b2, cnt, perm, pgate, out);
  }
}

// Round 3
// 364.781 us; speedup vs baseline: 2.4666x; 1.1501x over previous
//
#include <hip/hip_runtime.h>
#include <cstdint>
#include <cstddef>

#define D_ 1024
#define H_ 4096
#define E_ 16
#define B_ 2048

constexpr int CAP  = 384;   // per-expert slot capacity (mean 256, ~8 sigma)
constexpr int NSUB = 3;     // 3 x 128-row subtiles per block

typedef __attribute__((ext_vector_type(4))) float f32x4;
typedef __attribute__((ext_vector_type(8))) short bf16x8;

__device__ __forceinline__ unsigned short f2bf(float f) {
  unsigned u = __float_as_uint(f);
  u += 0x7fffu + ((u >> 16) & 1u);   // RNE
  return (unsigned short)(u >> 16);
}
__device__ __forceinline__ unsigned pack2(float a, float b) {
  return (unsigned)f2bf(a) | ((unsigned)f2bf(b) << 16);
}
__device__ __forceinline__ float bflo(unsigned u) { return __uint_as_float(u << 16); }
__device__ __forceinline__ float bfhi(unsigned u) { return __uint_as_float(u & 0xffff0000u); }

#define GLL16(g, l)                                                         \
  __builtin_amdgcn_global_load_lds(                                         \
      (const __attribute__((address_space(1))) void*)(g),                   \
      (__attribute__((address_space(3))) void*)(l), 16, 0, 0)

// ================= gating: LN(x)@norm(keys) -> top2 -> rmeta + bf16 X gather =================
__global__ __launch_bounds__(256) void moe_gating3(
    const float* __restrict__ x, const float* __restrict__ gamma,
    const float* __restrict__ beta, const float* __restrict__ keys,
    int* __restrict__ cnt, int4* __restrict__ rmi, float2* __restrict__ rmg,
    unsigned short* __restrict__ xg)
{
  const int b = blockIdx.x, t = threadIdx.x;
  const float4 xv = ((const float4*)(x + (size_t)b * D_))[t];  // d = 4t..4t+3
  float s  = xv.x + xv.y + xv.z + xv.w;
  float sq = xv.x*xv.x + xv.y*xv.y + xv.z*xv.z + xv.w*xv.w;
#pragma unroll
  for (int off = 32; off >= 1; off >>= 1) {
    s  += __shfl_down(s, off);
    sq += __shfl_down(sq, off);
  }
  __shared__ float ssum[4], ssq[4], sstat[2];
  if ((t & 63) == 0) { ssum[t >> 6] = s; ssq[t >> 6] = sq; }
  __syncthreads();
  if (t == 0) {
    float S = ssum[0] + ssum[1] + ssum[2] + ssum[3];
    float Q = ssq[0] + ssq[1] + ssq[2] + ssq[3];
    float mu  = S * (1.0f / D_);
    float var = Q * (1.0f / D_) - mu * mu;
    sstat[0] = mu; sstat[1] = rsqrtf(var + 1e-5f);
  }
  __syncthreads();
  const float mu = sstat[0], rstd = sstat[1];
  const float4 gv = ((const float4*)gamma)[t];
  const float4 bv = ((const float4*)beta)[t];
  float xn[4] = {(xv.x-mu)*rstd*gv.x+bv.x, (xv.y-mu)*rstd*gv.y+bv.y,
                 (xv.z-mu)*rstd*gv.z+bv.z, (xv.w-mu)*rstd*gv.w+bv.w};
  float acc[E_];
#pragma unroll
  for (int e2 = 0; e2 < E_; ++e2) acc[e2] = 0.f;
#pragma unroll
  for (int j = 0; j < 4; ++j) {
    const int d = 4*t + j;
    const float* kr = keys + (size_t)d * E_;
    float kv[E_];
#pragma unroll
    for (int e2 = 0; e2 < E_; ++e2) kv[e2] = kr[e2];
    float nq = 0.f;
#pragma unroll
    for (int e2 = 0; e2 < E_; ++e2) nq += kv[e2] * kv[e2];
    const float sc = xn[j] / fmaxf(sqrtf(nq), 1e-12f);
#pragma unroll
    for (int e2 = 0; e2 < E_; ++e2) acc[e2] += sc * kv[e2];
  }
  __shared__ float red[256][E_];
#pragma unroll
  for (int e2 = 0; e2 < E_; ++e2) red[t][e2] = acc[e2];
  __syncthreads();
  for (int s2 = 128; s2 >= 1; s2 >>= 1) {
    if (t < s2) {
#pragma unroll
      for (int e2 = 0; e2 < E_; ++e2) red[t][e2] += red[t + s2][e2];
    }
    __syncthreads();
  }
  __shared__ int sE[2], sP[2];
  if (t == 0) {
    float v0 = -1e30f; int e0 = 0;
    for (int e2 = 0; e2 < E_; ++e2) { float v = red[0][e2]; if (v > v0) { v0 = v; e0 = e2; } }
    float v1 = -1e30f; int e1 = 0;
    for (int e2 = 0; e2 < E_; ++e2) { if (e2 == e0) continue; float v = red[0][e2]; if (v > v1) { v1 = v; e1 = e2; } }
    const float g0 = 1.f / (1.f + __expf(v1 - v0));
    const float g1 = 1.f - g0;
    int p0 = atomicAdd(cnt + e0, 1); if (p0 >= CAP) p0 = CAP - 1;
    int p1 = atomicAdd(cnt + e1, 1); if (p1 >= CAP) p1 = CAP - 1;
    rmi[b] = make_int4(e0, p0, e1, p1);
    rmg[b] = make_float2(g0, g1);
    sE[0] = e0; sP[0] = p0;
    sE[1] = e1; sP[1] = p1;
  }
  __syncthreads();
  const uint2 pk = make_uint2(pack2(xv.x, xv.y), pack2(xv.z, xv.w));
#pragma unroll
  for (int i = 0; i < 2; ++i)
    ((uint2*)(xg + ((size_t)sE[i] * CAP + sP[i]) * D_))[t] = pk;
}

// ================= GEMM1: h = relu(Xg @ W1 + b1) -> hws bf16 =================
// grid 1024: N-tile 64 over H; block streams W1 panel once, loops 3x128 row subs.
__global__ __launch_bounds__(512, 4) void moe_g1k(
    const unsigned short* __restrict__ xg, const float* __restrict__ W1,
    const float* __restrict__ b1, unsigned short* __restrict__ hws)
{
  const int bx = blockIdx.x;
  const int slot7 = bx >> 3;                       // 0..127
  const int e  = ((bx & 7) << 1) + (slot7 >> 6);   // 2 experts per XCD
  const int nt = slot7 & 63;
  const int nb = nt * 64;

  const int t = threadIdx.x, w = t >> 6, lane = t & 63;
  const int l15 = lane & 15, l4 = lane >> 4;
  const int wr = w >> 2, wc = w & 3;               // waves 2(row) x 4(col16)
  const int cl = wc * 16 + l15;                    // col within 64

  __shared__ __align__(16) unsigned short As[2][NSUB * 128 * 32];  // 2x24 KiB
  __shared__ __align__(16) float Bsh[2][32 * 64];                  // 2x8 KiB

  const unsigned short* xge = xg + (size_t)e * CAP * D_;
  const float* W1e = W1 + (size_t)e * D_ * H_ + nb;

  const unsigned short* srcA[3];
  unsigned short* dstA[2][3];
#pragma unroll
  for (int i = 0; i < 3; ++i) {
    const int c = t + i * 512;
    srcA[i] = xge + (size_t)(c >> 2) * D_ + (c & 3) * 8;
    const int cb = i * 512 + w * 64;
    dstA[0][i] = &As[0][cb * 8];
    dstA[1][i] = &As[1][cb * 8];
  }
  const float* srcB = W1e + (size_t)(t >> 4) * H_ + (t & 15) * 4;
  float* dstB[2] = { &Bsh[0][w * 256], &Bsh[1][w * 256] };

  f32x4 acc[NSUB][4];
#pragma unroll
  for (int s = 0; s < NSUB; ++s)
#pragma unroll
    for (int rf = 0; rf < 4; ++rf) acc[s][rf] = f32x4{0,0,0,0};

#define STAGE1(kk, bsel) do {                                           \
    const int ko = (kk) * 32;                                           \
    _Pragma("unroll")                                                   \
    for (int i = 0; i < 3; ++i) GLL16(srcA[i] + ko, dstA[bsel][i]);     \
    GLL16(srcB + (size_t)ko * H_, dstB[bsel]);                          \
  } while (0)

  STAGE1(0, 0);
  for (int ph = 0; ph < 32; ++ph) {
    const int cur = ph & 1;
    if (ph + 1 < 32) {
      STAGE1(ph + 1, cur ^ 1);
      asm volatile("s_waitcnt vmcnt(4)" ::: "memory");
    } else {
      asm volatile("s_waitcnt vmcnt(0)" ::: "memory");
    }
    __builtin_amdgcn_s_barrier();
    const unsigned short* ap = As[cur];
    const float* bp = Bsh[cur];
    float bf[8];
#pragma unroll
    for (int j = 0; j < 8; ++j) bf[j] = bp[(l4 * 8 + j) * 64 + cl];
    union { unsigned u[4]; bf16x8 v; } BB;
#pragma unroll
    for (int i = 0; i < 4; ++i) BB.u[i] = pack2(bf[2*i], bf[2*i+1]);
#pragma unroll
    for (int s = 0; s < NSUB; ++s)
#pragma unroll
      for (int rf = 0; rf < 4; ++rf) {
        const bf16x8 a = *(const bf16x8*)&ap[(s * 128 + wr * 64 + rf * 16 + l15) * 32 + l4 * 8];
        acc[s][rf] = __builtin_amdgcn_mfma_f32_16x16x32_bf16(a, BB.v, acc[s][rf], 0, 0, 0);
      }
    __builtin_amdgcn_s_barrier();
  }
#undef STAGE1

  // epilogue: relu(acc + b1) -> hws bf16, pack 4 cols via shfl
  const float b1v = b1[e * H_ + nb + cl];
  unsigned short* hbase = hws + (size_t)e * CAP * H_ + nb + cl;
#pragma unroll
  for (int s = 0; s < NSUB; ++s)
#pragma unroll
    for (int rf = 0; rf < 4; ++rf)
#pragma unroll
      for (int r = 0; r < 4; ++r) {
        const int slot = s * 128 + wr * 64 + rf * 16 + l4 * 4 + r;
        float v = fmaxf(acc[s][rf][r] + b1v, 0.f);
        const unsigned u01 = pack2(v, __shfl_xor(v, 1));
        const float uo = __shfl_xor(__uint_as_float(u01), 2);
        if ((l15 & 3) == 0)
          *(uint2*)(hbase + (size_t)slot * H_) = make_uint2(u01, __float_as_uint(uo));
      }
}

// ================= GEMM2: eo = h @ W2 -> eo bf16 (no gate/bias here) =================
// grid 256: N-tile 64 over D; block streams W2 panel once, loops 3x128 row subs.
__global__ __launch_bounds__(512, 4) void moe_g2k(
    const unsigned short* __restrict__ hws, const float* __restrict__ W2,
    unsigned short* __restrict__ eo)
{
  const int bx = blockIdx.x;
  const int slot7 = bx >> 3;                       // 0..31
  const int e  = ((bx & 7) << 1) + (slot7 >> 4);
  const int nt = slot7 & 15;
  const int nb = nt * 64;

  const int t = threadIdx.x, w = t >> 6, lane = t & 63;
  const int l15 = lane & 15, l4 = lane >> 4;
  const int wr = w >> 2, wc = w & 3;
  const int cl = wc * 16 + l15;

  __shared__ __align__(16) unsigned short As[2][NSUB * 128 * 32];
  __shared__ __align__(16) float Bsh[2][32 * 64];

  const unsigned short* hwe = hws + (size_t)e * CAP * H_;
  const float* W2e = W2 + (size_t)e * H_ * D_ + nb;

  const unsigned short* srcA[3];
  unsigned short* dstA[2][3];
#pragma unroll
  for (int i = 0; i < 3; ++i) {
    const int c = t + i * 512;
    srcA[i] = hwe + (size_t)(c >> 2) * H_ + (c & 3) * 8;
    const int cb = i * 512 + w * 64;
    dstA[0][i] = &As[0][cb * 8];
    dstA[1][i] = &As[1][cb * 8];
  }
  const float* srcB = W2e + (size_t)(t >> 4) * D_ + (t & 15) * 4;
  float* dstB[2] = { &Bsh[0][w * 256], &Bsh[1][w * 256] };

  f32x4 acc[NSUB][4];
#pragma unroll
  for (int s = 0; s < NSUB; ++s)
#pragma unroll
    for (int rf = 0; rf < 4; ++rf) acc[s][rf] = f32x4{0,0,0,0};

#define STAGE2(kk, bsel) do {                                           \
    const int ko = (kk) * 32;                                           \
    _Pragma("unroll")                                                   \
    for (int i = 0; i < 3; ++i) GLL16(srcA[i] + ko, dstA[bsel][i]);     \
    GLL16(srcB + (size_t)ko * D_, dstB[bsel]);                          \
  } while (0)

  STAGE2(0, 0);
  for (int ph = 0; ph < 128; ++ph) {
    const int cur = ph & 1;
    if (ph + 1 < 128) {
      STAGE2(ph + 1, cur ^ 1);
      asm volatile("s_waitcnt vmcnt(4)" ::: "memory");
    } else {
      asm volatile("s_waitcnt vmcnt(0)" ::: "memory");
    }
    __builtin_amdgcn_s_barrier();
    const unsigned short* ap = As[cur];
    const float* bp = Bsh[cur];
    float bf[8];
#pragma unroll
    for (int j = 0; j < 8; ++j) bf[j] = bp[(l4 * 8 + j) * 64 + cl];
    union { unsigned u[4]; bf16x8 v; } BB;
#pragma unroll
    for (int i = 0; i < 4; ++i) BB.u[i] = pack2(bf[2*i], bf[2*i+1]);
#pragma unroll
    for (int s = 0; s < NSUB; ++s)
#pragma unroll
      for (int rf = 0; rf < 4; ++rf) {
        const bf16x8 a = *(const bf16x8*)&ap[(s * 128 + wr * 64 + rf * 16 + l15) * 32 + l4 * 8];
        acc[s][rf] = __builtin_amdgcn_mfma_f32_16x16x32_bf16(a, BB.v, acc[s][rf], 0, 0, 0);
      }
    __builtin_amdgcn_s_barrier();
  }
#undef STAGE2

  // epilogue: raw expert output -> eo bf16 (gate+b2 applied in combine)
  unsigned short* ebase = eo + (size_t)e * CAP * D_ + nb + cl;
#pragma unroll
  for (int s = 0; s < NSUB; ++s)
#pragma unroll
    for (int rf = 0; rf < 4; ++rf)
#pragma unroll
      for (int r = 0; r < 4; ++r) {
        const int slot = s * 128 + wr * 64 + rf * 16 + l4 * 4 + r;
        const float v = acc[s][rf][r];
        const unsigned u01 = pack2(v, __shfl_xor(v, 1));
        const float uo = __shfl_xor(__uint_as_float(u01), 2);
        if ((l15 & 3) == 0)
          *(uint2*)(ebase + (size_t)slot * D_) = make_uint2(u01, __float_as_uint(uo));
      }
}

// ================= combine: out[b] = g0*(eo0+b2[e0]) + g1*(eo1+b2[e1]) =================
__global__ __launch_bounds__(256) void moe_comb(
    const unsigned short* __restrict__ eo, const float* __restrict__ b2,
    const int4* __restrict__ rmi, const float2* __restrict__ rmg,
    float* __restrict__ out)
{
  const int b = blockIdx.x, t = threadIdx.x;
  const int4 m = rmi[b];
  const float2 g = rmg[b];
  const int c = t * 4;
  const uint2 ua = *(const uint2*)(eo + ((size_t)m.x * CAP + m.y) * D_ + c);
  const uint2 ub = *(const uint2*)(eo + ((size_t)m.z * CAP + m.w) * D_ + c);
  const float4 b2a = *(const float4*)(b2 + (size_t)m.x * D_ + c);
  const float4 b2b = *(const float4*)(b2 + (size_t)m.z * D_ + c);
  float4 o;
  o.x = g.x * (bflo(ua.x) + b2a.x) + g.y * (bflo(ub.x) + b2b.x);
  o.y = g.x * (bfhi(ua.x) + b2a.y) + g.y * (bfhi(ub.x) + b2b.y);
  o.z = g.x * (bflo(ua.y) + b2a.z) + g.y * (bflo(ub.y) + b2b.z);
  o.w = g.x * (bfhi(ua.y) + b2a.w) + g.y * (bfhi(ub.y) + b2b.w);
  *(float4*)(out + (size_t)b * D_ + c) = o;
}

// ======================= fallback path (round-1 fused kernels) =======================
constexpr int MROWS  = 64;
constexpr int HCHUNK = 256;
constexpr int HSPLIT = 4;
constexpr int HRANGE = H_ / HSPLIT;
constexpr int KSTEP  = 32;

__global__ __launch_bounds__(256) void moe_gating(
    const float* __restrict__ x, const float* __restrict__ gamma,
    const float* __restrict__ beta, const float* __restrict__ keys,
    int* __restrict__ cnt, int* __restrict__ perm, float* __restrict__ pgate)
{
  const int b = blockIdx.x, t = threadIdx.x;
  const float4 xv = ((const float4*)(x + (size_t)b * D_))[t];
  float s  = xv.x + xv.y + xv.z + xv.w;
  float sq = xv.x*xv.x + xv.y*xv.y + xv.z*xv.z + xv.w*xv.w;
#pragma unroll
  for (int off = 32; off >= 1; off >>= 1) {
    s  += __shfl_down(s, off);
    sq += __shfl_down(sq, off);
  }
  __shared__ float ssum[4], ssq[4], sstat[2];
  if ((t & 63) == 0) { ssum[t >> 6] = s; ssq[t >> 6] = sq; }
  __syncthreads();
  if (t == 0) {
    float S = ssum[0] + ssum[1] + ssum[2] + ssum[3];
    float Q = ssq[0] + ssq[1] + ssq[2] + ssq[3];
    float mu  = S * (1.0f / D_);
    float var = Q * (1.0f / D_) - mu * mu;
    sstat[0] = mu; sstat[1] = rsqrtf(var + 1e-5f);
  }
  __syncthreads();
  const float mu = sstat[0], rstd = sstat[1];
  const float4 gv = ((const float4*)gamma)[t];
  const float4 bv = ((const float4*)beta)[t];
  float xn[4] = {(xv.x-mu)*rstd*gv.x+bv.x, (xv.y-mu)*rstd*gv.y+bv.y,
                 (xv.z-mu)*rstd*gv.z+bv.z, (xv.w-mu)*rstd*gv.w+bv.w};
  float acc[E_];
#pragma unroll
  for (int e2 = 0; e2 < E_; ++e2) acc[e2] = 0.f;
#pragma unroll
  for (int j = 0; j < 4; ++j) {
    const int d = 4*t + j;
    const float* kr = keys + (size_t)d * E_;
    float kv[E_];
#pragma unroll
    for (int e2 = 0; e2 < E_; ++e2) kv[e2] = kr[e2];
    float nq = 0.f;
#pragma unroll
    for (int e2 = 0; e2 < E_; ++e2) nq += kv[e2] * kv[e2];
    const float sc = xn[j] / fmaxf(sqrtf(nq), 1e-12f);
#pragma unroll
    for (int e2 = 0; e2 < E_; ++e2) acc[e2] += sc * kv[e2];
  }
  __shared__ float red[256][E_];
#pragma unroll
  for (int e2 = 0; e2 < E_; ++e2) red[t][e2] = acc[e2];
  __syncthreads();
  for (int s2 = 128; s2 >= 1; s2 >>= 1) {
    if (t < s2) {
#pragma unroll
      for (int e2 = 0; e2 < E_; ++e2) red[t][e2] += red[t + s2][e2];
    }
    __syncthreads();
  }
  if (t == 0) {
    float v0 = -1e30f; int e0 = 0;
    for (int e2 = 0; e2 < E_; ++e2) { float v = red[0][e2]; if (v > v0) { v0 = v; e0 = e2; } }
    float v1 = -1e30f; int e1 = 0;
    for (int e2 = 0; e2 < E_; ++e2) { if (e2 == e0) continue; float v = red[0][e2]; if (v > v1) { v1 = v; e1 = e2; } }
    const float g0 = 1.f / (1.f + __expf(v1 - v0));
    const float g1 = 1.f - g0;
    int p0 = atomicAdd(cnt + e0, 1);
    perm[e0 * B_ + p0] = b; pgate[e0 * B_ + p0] = g0;
    int p1 = atomicAdd(cnt + e1, 1);
    perm[e1 * B_ + p1] = b; pgate[e1 * B_ + p1] = g1;
  }
}

__global__ __launch_bounds__(512, 2) void moe_ffn(
    const float* __restrict__ X,  const float* __restrict__ W1,
    const float* __restrict__ b1, const float* __restrict__ W2,
    const float* __restrict__ b2, const int* __restrict__ cnt,
    const int* __restrict__ perm, const float* __restrict__ pgate,
    float* __restrict__ out)
{
  const int bx = blockIdx.x;
  const int e  = bx >> 7;
  const int mt = (bx >> 2) & 31;
  const int hs = bx & 3;
  const int count = cnt[e];
  if (mt * MROWS >= count) return;

  const int t = threadIdx.x;
  const int w = t >> 6;
  const int lane = t & 63;
  const int l15 = lane & 15, l4 = lane >> 4;

  __shared__ __align__(16) unsigned short xs[MROWS * 40];
  __shared__ __align__(16) unsigned short wt1[HCHUNK * 40];
  __shared__ __align__(16) unsigned short wt2[D_ * 40];
  __shared__ __align__(16) unsigned short hbuf[MROWS * 264];
  __shared__ int   rows_s[MROWS];
  __shared__ float gate_s[MROWS];

  if (t < MROWS) {
    int slot = mt * MROWS + t;
    int idx  = slot < count ? slot : count - 1;
    rows_s[t] = perm[e * B_ + idx];
    gate_s[t] = (slot < count) ? pgate[e * B_ + idx] : 0.f;
  }
  __syncthreads();

  f32x4 oacc[4][8];
#pragma unroll
  for (int a = 0; a < 4; ++a)
#pragma unroll
    for (int c = 0; c < 8; ++c) oacc[a][c] = f32x4{0.f, 0.f, 0.f, 0.f};

  const float* W1e = W1 + (size_t)e * D_ * H_;
  const float* W2e = W2 + (size_t)e * H_ * D_;
  const int hbase0 = hs * HRANGE;

  const int xrow = t >> 3, xq = t & 7;
  const size_t xgbase = (size_t)rows_s[xrow] * D_ + xq * 4;

  for (int ch = 0; ch < HRANGE / HCHUNK; ++ch) {
    const int hb = hbase0 + ch * HCHUNK;
    f32x4 hacc[4][2];
#pragma unroll
    for (int a = 0; a < 4; ++a)
#pragma unroll
      for (int c = 0; c < 2; ++c) hacc[a][c] = f32x4{0.f, 0.f, 0.f, 0.f};

    for (int kk = 0; kk < D_ / KSTEP; ++kk) {
      {
        const float4 v = *(const float4*)(X + xgbase + kk * KSTEP);
        *(uint2*)((char*)xs + xrow * 80 + xq * 8) =
            make_uint2(pack2(v.x, v.y), pack2(v.z, v.w));
      }
#pragma unroll
      for (int i = 0; i < 2; ++i) {
        const int p = t + i * 512;
        const int n = p & 255, koct = p >> 8;
        const float* src = W1e + (size_t)(kk * KSTEP + koct * 8) * H_ + (hb + n);
        float f0 = src[0],      f1 = src[H_],     f2 = src[2*H_],  f3 = src[3*H_];
        float f4 = src[4*H_],   f5 = src[5*H_],   f6 = src[6*H_],  f7 = src[7*H_];
        *(uint4*)((char*)wt1 + n * 80 + koct * 16) =
            make_uint4(pack2(f0,f1), pack2(f2,f3), pack2(f4,f5), pack2(f6,f7));
      }
      __syncthreads();
      bf16x8 af[4];
#pragma unroll
      for (int rf = 0; rf < 4; ++rf)
        af[rf] = *(const bf16x8*)((const char*)xs + (rf*16 + l15) * 80 + l4 * 16);
#pragma unroll
      for (int cf = 0; cf < 2; ++cf) {
        const bf16x8 bfr = *(const bf16x8*)((const char*)wt1 + (w*32 + cf*16 + l15) * 80 + l4 * 16);
#pragma unroll
        for (int rf = 0; rf < 4; ++rf)
          hacc[rf][cf] = __builtin_amdgcn_mfma_f32_16x16x32_bf16(af[rf], bfr, hacc[rf][cf], 0, 0, 0);
      }
      __syncthreads();
    }

#pragma unroll
    for (int cf = 0; cf < 2; ++cf) {
      const int col = w*32 + cf*16 + l15;
      const float bias = b1[e * H_ + hb + col];
#pragma unroll
      for (int rf = 0; rf < 4; ++rf)
#pragma unroll
        for (int r = 0; r < 4; ++r) {
          const int row = rf*16 + l4*4 + r;
          float v = hacc[rf][cf][r] + bias;
          v = fmaxf(v, 0.f);
          *((unsigned short*)((char*)hbuf + row * 528 + col * 2)) = f2bf(v);
        }
    }
    __syncthreads();

    for (int kk2 = 0; kk2 < HCHUNK / KSTEP; ++kk2) {
      const int habs = hb + kk2 * KSTEP;
#pragma unroll 4
      for (int i = 0; i < 8; ++i) {
        const int p = t + i * 512;
        const int n = p & 1023, koct = p >> 10;
        const float* src = W2e + (size_t)(habs + koct * 8) * D_ + n;
        float f0 = src[0],      f1 = src[D_],     f2 = src[2*D_],  f3 = src[3*D_];
        float f4 = src[4*D_],   f5 = src[5*D_],   f6 = src[6*D_],  f7 = src[7*D_];
        *(uint4*)((char*)wt2 + n * 80 + koct * 16) =
            make_uint4(pack2(f0,f1), pack2(f2,f3), pack2(f4,f5), pack2(f6,f7));
      }
      __syncthreads();
      bf16x8 af2[4];
#pragma unroll
      for (int rf = 0; rf < 4; ++rf)
        af2[rf] = *(const bf16x8*)((const char*)hbuf + (rf*16 + l15) * 528 + kk2 * 64 + l4 * 16);
#pragma unroll
      for (int cf = 0; cf < 8; ++cf) {
        const bf16x8 bfr = *(const bf16x8*)((const char*)wt2 + (w*128 + cf*16 + l15) * 80 + l4 * 16);
#pragma unroll
        for (int rf = 0; rf < 4; ++rf)
          oacc[rf][cf] = __builtin_amdgcn_mfma_f32_16x16x32_bf16(af2[rf], bfr, oacc[rf][cf], 0, 0, 0);
      }
      __syncthreads();
    }
  }

  int   rg[16];
  float gg[16];
#pragma unroll
  for (int rf = 0; rf < 4; ++rf)
#pragma unroll
    for (int r = 0; r < 4; ++r) {
      const int sl = rf*16 + l4*4 + r;
      rg[rf*4+r] = rows_s[sl];
      gg[rf*4+r] = gate_s[sl];
    }
#pragma unroll
  for (int cf = 0; cf < 8; ++cf) {
    const int col = w*128 + cf*16 + l15;
    const float b2v = (hs == 0) ? b2[e * D_ + col] : 0.f;
#pragma unroll
    for (int rf = 0; rf < 4; ++rf)
#pragma unroll
      for (int r = 0; r < 4; ++r) {
        const float v = (oacc[rf][cf][r] + b2v) * gg[rf*4+r];
        atomicAdd(out + (size_t)rg[rf*4+r] * D_ + col, v);
      }
  }
}

// ======================= launch =======================
extern "C" void kernel_launch(void* const* d_in, const int* in_sizes, int n_in,
                              void* d_out, int out_size, void* d_ws, size_t ws_size,
                              hipStream_t stream) {
  const float* x     = (const float*)d_in[0];
  const float* gamma = (const float*)d_in[1];
  const float* beta  = (const float*)d_in[2];
  const float* keys  = (const float*)d_in[3];
  const float* W1    = (const float*)d_in[4];
  const float* b1    = (const float*)d_in[5];
  const float* W2    = (const float*)d_in[6];
  const float* b2    = (const float*)d_in[7];
  float* out = (float*)d_out;

  char* ws = (char*)d_ws;

  // primary-path layout
  const size_t OFF_RMI = 256;                                   // 2048*16
  const size_t OFF_RMG = OFF_RMI + (size_t)B_ * 16;             // 2048*8
  const size_t OFF_XG  = OFF_RMG + (size_t)B_ * 8;              // 49408
  const size_t XG_SZ   = (size_t)E_ * CAP * D_ * 2;             // 12 MiB (eo overlays)
  const size_t OFF_HW  = OFF_XG + XG_SZ;
  const size_t NEED    = OFF_HW + (size_t)E_ * CAP * H_ * 2;    // ~60.05 MiB

  int* cnt = (int*)ws;
  (void)hipMemsetAsync(cnt, 0, E_ * sizeof(int), stream);

  if (ws_size >= NEED) {
    int4*   rmi = (int4*)(ws + OFF_RMI);
    float2* rmg = (float2*)(ws + OFF_RMG);
    unsigned short* xg  = (unsigned short*)(ws + OFF_XG);
    unsigned short* eo  = xg;   // overlay: xg dead after g1k
    unsigned short* hws = (unsigned short*)(ws + OFF_HW);

    moe_gating3<<<B_, 256, 0, stream>>>(x, gamma, beta, keys, cnt, rmi, rmg, xg);
    moe_g1k<<<E_ * 64, 512, 0, stream>>>(xg, W1, b1, hws);
    moe_g2k<<<E_ * 16, 512, 0, stream>>>(hws, W2, eo);
    moe_comb<<<B_, 256, 0, stream>>>(eo, b2, rmi, rmg, out);
  } else {
    int*   perm  = (int*)(ws + 256);
    float* pgate = (float*)(ws + 256 + 131072);
    (void)hipMemsetAsync(d_out, 0, (size_t)B_ * D_ * sizeof(float), stream);
    moe_gating<<<B_, 256, 0, stream>>>(x, gamma, beta, keys, cnt, perm, pgate);
    moe_ffn<<<E_ * 32 * HSPLIT, 512, 0, stream>>>(x, W1, b1, W2, b2, cnt, perm, pgate, out);
  }
}